// Round 4
// baseline (166.706 us; speedup 1.0000x reference)
//
#include <hip/hip_runtime.h>

// B=512, N=64, H=256, LAT=128, HEADS=4, HC=64, NF=64, L=3, R=8, SCAL=2.0, NB=4, Din=384

typedef float float4v __attribute__((ext_vector_type(4)));
typedef short short8v __attribute__((ext_vector_type(8)));

struct alignas(8) us4 { ushort x, y, z, w; };

// f32 ws offsets (in floats)
#define ZA_OFF 0UL          // zA[512][8]
// ushort ws offsets (in ushorts)
#define XBF_U   46080UL     // x bf16 [512][64][256]
#define ZBF_U   8434688UL   // z bf16 [512][128]
#define GWBF_U  8500224UL   // gatW bf16 [3][256][384]
#define WZBF_U  8795136UL   // z2n_w bf16 [16384][128]
#define PW_U    10892288UL  // pred weights bf16 [80][256]

__device__ inline ushort f2bf(float f) {
    uint u = __float_as_uint(f);
    uint r = (u + 0x7FFFu + ((u >> 16) & 1u)) >> 16;
    return (ushort)r;
}
__device__ inline float bf2f(ushort u) { return __uint_as_float(((uint)u) << 16); }

// ---------------------------------------------------------------- setup ----
__global__ __launch_bounds__(256) void k_setup(
    const float* __restrict__ z, const float* __restrict__ z2nA,
    const float* __restrict__ nodeW, const float* __restrict__ nodeA, const float* __restrict__ nodeB,
    const float* __restrict__ adjW, const float* __restrict__ adjA, const float* __restrict__ adjB,
    const float* __restrict__ bondW, const float* __restrict__ bondA, const float* __restrict__ bondB,
    const float* __restrict__ gatW, const float* __restrict__ z2nw,
    float* __restrict__ wsf)
{
    ushort* wsu = (ushort*)wsf;
    int gid = blockIdx.x * 256 + threadIdx.x;
    if (gid < 4096) {                       // zA[b][r] = z[b]·A[r]
        int b = gid >> 3, r = gid & 7;
        const float* zp = z + (size_t)b * 128;
        const float* ap = z2nA + (size_t)r * 128;
        float s = 0.f;
        #pragma unroll 8
        for (int k = 0; k < 128; ++k) s += zp[k] * ap[k];
        wsf[ZA_OFF + gid] = s;
    } else if (gid < 24576) {               // pw[80][256] bf16, LoRA folded
        int idx = gid - 4096;
        int r = idx >> 8, c = idx & 255;
        float v = 0.f;
        if (r < 64) {
            float s = 0.f;
            #pragma unroll
            for (int k = 0; k < 8; ++k) s += nodeB[r*8+k] * nodeA[k*256+c];
            v = nodeW[r*256+c] + 2.0f * s;
        } else if (r < 66) {
            int off = (r - 64) * 256 + c;
            float s = 0.f;
            #pragma unroll
            for (int k = 0; k < 8; ++k) s += adjB[k] * adjA[k*512+off];
            v = adjW[off] + 2.0f * s;
        } else if (r < 70) {
            int q = r - 66;
            float s = 0.f;
            #pragma unroll
            for (int k = 0; k < 8; ++k) s += bondB[q*8+k] * bondA[k*512+c];
            v = bondW[q*512+c] + 2.0f * s;
        } else if (r < 74) {
            int q = r - 70;
            float s = 0.f;
            #pragma unroll
            for (int k = 0; k < 8; ++k) s += bondB[q*8+k] * bondA[k*512+256+c];
            v = bondW[q*512+256+c] + 2.0f * s;
        }
        wsu[PW_U + idx] = f2bf(v);
    } else {                                // f32 -> bf16 conversions, 4/thread
        int cid = gid - 24576;
        const float* src; ushort* dst; int idx;
        if (cid < 16384)        { src = z;     dst = wsu + ZBF_U;  idx = cid; }
        else if (cid < 90112)   { src = gatW;  dst = wsu + GWBF_U; idx = cid - 16384; }
        else if (cid < 614400)  { src = z2nw;  dst = wsu + WZBF_U; idx = cid - 90112; }
        else return;
        float4 v = ((const float4*)src)[idx];
        us4 o; o.x = f2bf(v.x); o.y = f2bf(v.y); o.z = f2bf(v.z); o.w = f2bf(v.w);
        ((us4*)dst)[idx] = o;
    }
}

// ------------------------------------------------------------- z_to_nodes --
__global__ __launch_bounds__(256) void k_z2n(
    const float* __restrict__ bias, const float* __restrict__ lB,
    float* __restrict__ wsf)
{
    ushort* wsu = (ushort*)wsf;
    int t = threadIdx.x;
    int w = t >> 6, ln = t & 63, lo = ln & 15, hi = ln >> 4;
    int bm = blockIdx.x >> 6, bn = blockIdx.x & 63;
    int brow0 = bm * 64;
    int o0 = bn * 256 + w * 64;
    const ushort* wz = wsu + WZBF_U;
    const ushort* zb = wsu + ZBF_U;
    float4v acc[4][4];
    #pragma unroll
    for (int m = 0; m < 4; ++m)
        #pragma unroll
        for (int n = 0; n < 4; ++n) acc[m][n] = (float4v)(0.f);
    #pragma unroll
    for (int kk = 0; kk < 4; ++kk) {
        short8v a[4], bq[4];
        #pragma unroll
        for (int m = 0; m < 4; ++m)
            a[m] = *(const short8v*)(wz + (size_t)(o0 + m*16 + lo)*128 + kk*32 + hi*8);
        #pragma unroll
        for (int n = 0; n < 4; ++n)
            bq[n] = *(const short8v*)(zb + (size_t)(brow0 + n*16 + lo)*128 + kk*32 + hi*8);
        #pragma unroll
        for (int m = 0; m < 4; ++m)
            #pragma unroll
            for (int n = 0; n < 4; ++n)
                acc[m][n] = __builtin_amdgcn_mfma_f32_16x16x32_bf16(a[m], bq[n], acc[m][n], 0, 0, 0);
    }
    const float* zA = wsf + ZA_OFF;
    float4 za0[4], za1[4];
    #pragma unroll
    for (int n = 0; n < 4; ++n) {
        int brow = brow0 + n*16 + lo;
        za0[n] = *(const float4*)&zA[brow*8];
        za1[n] = *(const float4*)&zA[brow*8 + 4];
    }
    #pragma unroll
    for (int m = 0; m < 4; ++m) {
        float lor[4][4]; float bs[4];
        #pragma unroll
        for (int q = 0; q < 4; ++q) {
            int o = o0 + m*16 + hi*4 + q;
            float4 b20 = *(const float4*)&lB[(size_t)o*8];
            float4 b21 = *(const float4*)&lB[(size_t)o*8 + 4];
            bs[q] = bias[o];
            #pragma unroll
            for (int n = 0; n < 4; ++n)
                lor[n][q] = za0[n].x*b20.x + za0[n].y*b20.y + za0[n].z*b20.z + za0[n].w*b20.w
                          + za1[n].x*b21.x + za1[n].y*b21.y + za1[n].z*b21.z + za1[n].w*b21.w;
        }
        #pragma unroll
        for (int n = 0; n < 4; ++n) {
            int brow = brow0 + n*16 + lo;
            float v0 = acc[m][n][0] + 2.f*lor[n][0] + bs[0]; v0 = v0 > 0.f ? v0 : 0.f;
            float v1 = acc[m][n][1] + 2.f*lor[n][1] + bs[1]; v1 = v1 > 0.f ? v1 : 0.f;
            float v2 = acc[m][n][2] + 2.f*lor[n][2] + bs[2]; v2 = v2 > 0.f ? v2 : 0.f;
            float v3 = acc[m][n][3] + 2.f*lor[n][3] + bs[3]; v3 = v3 > 0.f ? v3 : 0.f;
            us4 pk; pk.x = f2bf(v0); pk.y = f2bf(v1); pk.z = f2bf(v2); pk.w = f2bf(v3);
            *(us4*)(wsu + XBF_U + (size_t)brow*16384 + o0 + m*16 + hi*4) = pk;
        }
    }
}

// ----------------------------------------------------- fused GAT layer -----
// grid=512 (one block per graph), 8 waves: wave = (head, node-half).
// No max-subtraction: p = exp(leaky(e)) directly, normalize by sum at end.
__global__ __launch_bounds__(512, 4) void k_gat(
    const float* __restrict__ asrc_all, const float* __restrict__ adst_all,
    const float* __restrict__ gbias, int l, float* __restrict__ wsf)
{
    __shared__ ushort hT[4][64][72];          // hT[head][c][j] bf16
    __shared__ float es[4][64], ed[4][64];
    ushort* wsu = (ushort*)wsf;
    int t = threadIdx.x;
    int w = t >> 6, ln = t & 63, lo = ln & 15, hi = ln >> 4;
    int head = w & 3, m0 = (w >> 2) * 32;
    int b = blockIdx.x;
    const ushort* xb  = wsu + XBF_U + (size_t)b * 16384;
    const ushort* zbp = wsu + ZBF_U + (size_t)b * 128;
    const ushort* wl  = wsu + GWBF_U + (size_t)l * 98304 + (size_t)head * 24576;

    // ---- h-GEMM slice: rows [m0, m0+32), cols = head's 64 channels, K=384
    float4v acc[2][4];
    #pragma unroll
    for (int m = 0; m < 2; ++m)
        #pragma unroll
        for (int n = 0; n < 4; ++n) acc[m][n] = (float4v)(0.f);
    #pragma unroll
    for (int kk = 0; kk < 12; ++kk) {
        short8v a[2], bq[4];
        if (kk < 8) {
            a[0] = *(const short8v*)(xb + (size_t)(m0 + lo)*256 + kk*32 + hi*8);
            a[1] = *(const short8v*)(xb + (size_t)(m0 + 16 + lo)*256 + kk*32 + hi*8);
        } else {
            short8v az = *(const short8v*)(zbp + (kk-8)*32 + hi*8);
            a[0] = az; a[1] = az;
        }
        #pragma unroll
        for (int n = 0; n < 4; ++n)
            bq[n] = *(const short8v*)(wl + (size_t)(n*16 + lo)*384 + kk*32 + hi*8);
        #pragma unroll
        for (int m = 0; m < 2; ++m)
            #pragma unroll
            for (int n = 0; n < 4; ++n)
                acc[m][n] = __builtin_amdgcn_mfma_f32_16x16x32_bf16(a[m], bq[n], acc[m][n], 0, 0, 0);
    }

    // ---- e-dots for my 32 rows (reduce over channels = (n, lo))
    float asv[4], adv[4];
    #pragma unroll
    for (int n = 0; n < 4; ++n) {
        asv[n] = asrc_all[l*256 + head*64 + n*16 + lo];
        adv[n] = adst_all[l*256 + head*64 + n*16 + lo];
    }
    #pragma unroll
    for (int m = 0; m < 2; ++m) {
        float ps0=0,ps1=0,ps2=0,ps3=0, pd0=0,pd1=0,pd2=0,pd3=0;
        #pragma unroll
        for (int n = 0; n < 4; ++n) {
            ps0 += acc[m][n][0]*asv[n]; pd0 += acc[m][n][0]*adv[n];
            ps1 += acc[m][n][1]*asv[n]; pd1 += acc[m][n][1]*adv[n];
            ps2 += acc[m][n][2]*asv[n]; pd2 += acc[m][n][2]*adv[n];
            ps3 += acc[m][n][3]*asv[n]; pd3 += acc[m][n][3]*adv[n];
        }
        #pragma unroll
        for (int mask = 1; mask < 16; mask <<= 1) {
            ps0 += __shfl_xor(ps0, mask); pd0 += __shfl_xor(pd0, mask);
            ps1 += __shfl_xor(ps1, mask); pd1 += __shfl_xor(pd1, mask);
            ps2 += __shfl_xor(ps2, mask); pd2 += __shfl_xor(pd2, mask);
            ps3 += __shfl_xor(ps3, mask); pd3 += __shfl_xor(pd3, mask);
        }
        if (lo == 0) {
            *(float4*)&es[head][m0 + m*16 + hi*4] = make_float4(ps0, ps1, ps2, ps3);
            *(float4*)&ed[head][m0 + m*16 + hi*4] = make_float4(pd0, pd1, pd2, pd3);
        }
    }

    // ---- hT[c][j] for my node half
    #pragma unroll
    for (int m = 0; m < 2; ++m)
        #pragma unroll
        for (int n = 0; n < 4; ++n) {
            us4 pk;
            pk.x = f2bf(acc[m][n][0]); pk.y = f2bf(acc[m][n][1]);
            pk.z = f2bf(acc[m][n][2]); pk.w = f2bf(acc[m][n][3]);
            *(us4*)&hT[head][n*16 + lo][m0 + m*16 + hi*4] = pk;
        }

    __syncthreads();

    // ---- PV (swapped): out^T[c][r] = sum_j h[j][c] * p[r][j];  p = exp(leaky(e))
    float4v acc2[4][2];
    #pragma unroll
    for (int m = 0; m < 4; ++m)
        #pragma unroll
        for (int n = 0; n < 2; ++n) acc2[m][n] = (float4v)(0.f);
    float psum[2] = {0.f, 0.f};
    #pragma unroll
    for (int kk = 0; kk < 2; ++kk) {
        short8v hb[4];
        #pragma unroll
        for (int m = 0; m < 4; ++m)
            hb[m] = *(const short8v*)&hT[head][m*16 + lo][kk*32 + hi*8];
        float4 e0 = *(const float4*)&es[head][kk*32 + hi*8];
        float4 e1 = *(const float4*)&es[head][kk*32 + hi*8 + 4];
        float ej[8] = {e0.x, e0.y, e0.z, e0.w, e1.x, e1.y, e1.z, e1.w};
        #pragma unroll
        for (int n = 0; n < 2; ++n) {
            float edr = ed[head][m0 + n*16 + lo];
            short8v af; float pp = 0.f;
            #pragma unroll
            for (int jj = 0; jj < 8; ++jj) {
                float e = edr + ej[jj];
                e = fmaxf(e, 0.2f * e);
                float p = __expf(e);
                pp += p;
                af[jj] = (short)f2bf(p);
            }
            psum[n] += pp;
            #pragma unroll
            for (int m = 0; m < 4; ++m)
                acc2[m][n] = __builtin_amdgcn_mfma_f32_16x16x32_bf16(hb[m], af, acc2[m][n], 0, 0, 0);
        }
    }
    float rs[2];
    #pragma unroll
    for (int n = 0; n < 2; ++n) {
        psum[n] += __shfl_xor(psum[n], 16);
        psum[n] += __shfl_xor(psum[n], 32);
        rs[n] = 1.0f / psum[n];
    }

    // ---- epilogue: normalize, +bias, relu, bf16 packed store
    #pragma unroll
    for (int m = 0; m < 4; ++m) {
        int c0 = head*64 + m*16 + hi*4;
        float b0 = gbias[l*256 + c0 + 0];
        float b1 = gbias[l*256 + c0 + 1];
        float b2 = gbias[l*256 + c0 + 2];
        float b3 = gbias[l*256 + c0 + 3];
        #pragma unroll
        for (int n = 0; n < 2; ++n) {
            int r = m0 + n*16 + lo;
            float v0 = acc2[m][n][0]*rs[n] + b0; v0 = v0 > 0.f ? v0 : 0.f;
            float v1 = acc2[m][n][1]*rs[n] + b1; v1 = v1 > 0.f ? v1 : 0.f;
            float v2 = acc2[m][n][2]*rs[n] + b2; v2 = v2 > 0.f ? v2 : 0.f;
            float v3 = acc2[m][n][3]*rs[n] + b3; v3 = v3 > 0.f ? v3 : 0.f;
            us4 pk; pk.x = f2bf(v0); pk.y = f2bf(v1); pk.z = f2bf(v2); pk.w = f2bf(v3);
            *(us4*)(wsu + XBF_U + (size_t)b*16384 + (size_t)r*256 + c0) = pk;
        }
    }
}

// ------------------------------------------------------------- predictors --
__global__ __launch_bounds__(256) void k_pred(
    const float* __restrict__ nodeb, const float* __restrict__ adjb,
    const float* __restrict__ bondb, const float* __restrict__ wsf,
    float* __restrict__ out)
{
    __shared__ float s1l[64], s2l[64];
    __shared__ float t1l[64][5], t2l[64][5];
    const ushort* wsu = (const ushort*)wsf;
    int t = threadIdx.x;
    int w = t >> 6, ln = t & 63, lo = ln & 15, hi = ln >> 4;
    int b = blockIdx.x;
    const ushort* xb = wsu + XBF_U + (size_t)b * 16384;
    const ushort* pw = wsu + PW_U;

    float4v acc[5];
    #pragma unroll
    for (int n = 0; n < 5; ++n) acc[n] = (float4v)(0.f);
    #pragma unroll
    for (int kk = 0; kk < 8; ++kk) {
        short8v a = *(const short8v*)(xb + (size_t)(w*16 + lo)*256 + kk*32 + hi*8);
        #pragma unroll
        for (int n = 0; n < 5; ++n) {
            short8v bq = *(const short8v*)(pw + (size_t)(n*16 + lo)*256 + kk*32 + hi*8);
            acc[n] = __builtin_amdgcn_mfma_f32_16x16x32_bf16(a, bq, acc[n], 0, 0, 0);
        }
    }

    #pragma unroll
    for (int n = 0; n < 4; ++n) {
        float bs = nodeb[n*16 + lo];
        #pragma unroll
        for (int q = 0; q < 4; ++q) {
            int nd = w*16 + hi*4 + q;
            out[(size_t)b*4096 + (size_t)nd*64 + n*16 + lo] = acc[n][q] + bs;
        }
    }
    #pragma unroll
    for (int q = 0; q < 4; ++q) {
        int nd = w*16 + hi*4 + q;
        float v = acc[4][q];
        if (lo == 0)      s1l[nd] = v;
        else if (lo == 1) s2l[nd] = v;
        else if (lo < 6)  t1l[nd][lo-2] = v;
        else if (lo < 10) t2l[nd][lo-6] = v;
    }
    __syncthreads();

    float ab = adjb[0];
    #pragma unroll
    for (int it = 0; it < 4; ++it) {
        int flat = (it*256 + t) * 4;
        int i = flat >> 6;
        int j0 = flat & 63;
        float4 v; float* vp = (float*)&v;
        #pragma unroll
        for (int uu = 0; uu < 4; ++uu) {
            int j = j0 + uu;
            float val;
            if (i == j)      val = 0.f;
            else if (i < j)  val = s1l[i] + s2l[j] + ab;
            else             val = s1l[j] + s2l[i] + ab;
            vp[uu] = val;
        }
        *(float4*)&out[2097152UL + (size_t)b*4096 + flat] = v;
    }

    float4 bb = *(const float4*)bondb;
    #pragma unroll
    for (int it = 0; it < 16; ++it) {
        int fl4 = it*256 + t;
        int i = fl4 >> 6;
        int j = fl4 & 63;
        float4 v;
        if (i == j) { v.x = v.y = v.z = v.w = 0.f; }
        else {
            int a = i < j ? i : j, c = i < j ? j : i;
            v.x = t1l[a][0] + t2l[c][0] + bb.x;
            v.y = t1l[a][1] + t2l[c][1] + bb.y;
            v.z = t1l[a][2] + t2l[c][2] + bb.z;
            v.w = t1l[a][3] + t2l[c][3] + bb.w;
        }
        *(float4*)&out[4194304UL + (size_t)b*16384 + (size_t)fl4*4] = v;
    }
}

// ------------------------------------------------------------------ host ---
extern "C" void kernel_launch(void* const* d_in, const int* in_sizes, int n_in,
                              void* d_out, int out_size, void* d_ws, size_t ws_size,
                              hipStream_t stream)
{
    const float* z     = (const float*)d_in[0];
    const float* z2nw  = (const float*)d_in[1];
    const float* z2nb  = (const float*)d_in[2];
    const float* z2nA  = (const float*)d_in[3];
    const float* z2nB  = (const float*)d_in[4];
    const float* gatW  = (const float*)d_in[5];
    const float* asrc  = (const float*)d_in[6];
    const float* adst  = (const float*)d_in[7];
    const float* gbias = (const float*)d_in[8];
    const float* nodew = (const float*)d_in[9];
    const float* nodeb = (const float*)d_in[10];
    const float* nodeA = (const float*)d_in[11];
    const float* nodeB = (const float*)d_in[12];
    const float* adjw  = (const float*)d_in[13];
    const float* adjb  = (const float*)d_in[14];
    const float* adjA  = (const float*)d_in[15];
    const float* adjB  = (const float*)d_in[16];
    const float* bondw = (const float*)d_in[17];
    const float* bondb = (const float*)d_in[18];
    const float* bondA = (const float*)d_in[19];
    const float* bondB = (const float*)d_in[20];
    float* ws  = (float*)d_ws;
    float* out = (float*)d_out;

    k_setup<<<2496, 256, 0, stream>>>(z, z2nA, nodew, nodeA, nodeB,
                                      adjw, adjA, adjB, bondw, bondA, bondB,
                                      gatW, z2nw, ws);
    k_z2n<<<512, 256, 0, stream>>>(z2nb, z2nB, ws);
    for (int l = 0; l < 3; ++l)
        k_gat<<<512, 512, 0, stream>>>(asrc, adst, gbias, l, ws);
    k_pred<<<512, 256, 0, stream>>>(nodeb, adjb, bondb, ws, out);
}

// Round 5
// 124.813 us; speedup vs baseline: 1.3356x; 1.3356x over previous
//
#include <hip/hip_runtime.h>

// B=512, N=64, H=256, LAT=128, HEADS=4, HC=64, NF=64, L=3, R=8, SCAL=2.0, NB=4, Din=384

typedef float float4v __attribute__((ext_vector_type(4)));
typedef short short8v __attribute__((ext_vector_type(8)));

struct alignas(8) us4 { ushort x, y, z, w; };

// f32 ws offsets (in floats)
#define ZA_OFF 0UL          // zA[512][8]
// ushort ws offsets (in ushorts)
#define XBF_U   46080UL     // x bf16 [512][64][256]
#define ZBF_U   8434688UL   // z bf16 [512][128]
#define GWBF_U  8500224UL   // gatW bf16 [3][256][384]
#define WZBF_U  8795136UL   // z2n_w bf16 [16384][128]
#define PW_U    10892288UL  // pred weights bf16 [80][256]

__device__ inline ushort f2bf(float f) {
    uint u = __float_as_uint(f);
    uint r = (u + 0x7FFFu + ((u >> 16) & 1u)) >> 16;
    return (ushort)r;
}
__device__ inline float bf2f(ushort u) { return __uint_as_float(((uint)u) << 16); }

// swizzled x-mode LDS index (ushort units): row r (0..63), ushort col cu (0..255)
__device__ inline int xidx(int r, int cu) {
    int ch = cu >> 3;
    return r * 256 + (((ch ^ (r & 7))) << 3) + (cu & 7);
}

// ---------------------------------------------------------------- setup ----
__global__ __launch_bounds__(256) void k_setup(
    const float* __restrict__ z, const float* __restrict__ z2nA,
    const float* __restrict__ nodeW, const float* __restrict__ nodeA, const float* __restrict__ nodeB,
    const float* __restrict__ adjW, const float* __restrict__ adjA, const float* __restrict__ adjB,
    const float* __restrict__ bondW, const float* __restrict__ bondA, const float* __restrict__ bondB,
    const float* __restrict__ gatW, const float* __restrict__ z2nw,
    float* __restrict__ wsf)
{
    ushort* wsu = (ushort*)wsf;
    int gid = blockIdx.x * 256 + threadIdx.x;
    if (gid < 4096) {                       // zA[b][r] = z[b]·A[r]
        int b = gid >> 3, r = gid & 7;
        const float* zp = z + (size_t)b * 128;
        const float* ap = z2nA + (size_t)r * 128;
        float s = 0.f;
        #pragma unroll 8
        for (int k = 0; k < 128; ++k) s += zp[k] * ap[k];
        wsf[ZA_OFF + gid] = s;
    } else if (gid < 24576) {               // pw[80][256] bf16, LoRA folded
        int idx = gid - 4096;
        int r = idx >> 8, c = idx & 255;
        float v = 0.f;
        if (r < 64) {
            float s = 0.f;
            #pragma unroll
            for (int k = 0; k < 8; ++k) s += nodeB[r*8+k] * nodeA[k*256+c];
            v = nodeW[r*256+c] + 2.0f * s;
        } else if (r < 66) {
            int off = (r - 64) * 256 + c;
            float s = 0.f;
            #pragma unroll
            for (int k = 0; k < 8; ++k) s += adjB[k] * adjA[k*512+off];
            v = adjW[off] + 2.0f * s;
        } else if (r < 70) {
            int q = r - 66;
            float s = 0.f;
            #pragma unroll
            for (int k = 0; k < 8; ++k) s += bondB[q*8+k] * bondA[k*512+c];
            v = bondW[q*512+c] + 2.0f * s;
        } else if (r < 74) {
            int q = r - 70;
            float s = 0.f;
            #pragma unroll
            for (int k = 0; k < 8; ++k) s += bondB[q*8+k] * bondA[k*512+256+c];
            v = bondW[q*512+256+c] + 2.0f * s;
        }
        wsu[PW_U + idx] = f2bf(v);
    } else {                                // f32 -> bf16 conversions, 4/thread
        int cid = gid - 24576;
        const float* src; ushort* dst; int idx;
        if (cid < 16384)        { src = z;     dst = wsu + ZBF_U;  idx = cid; }
        else if (cid < 90112)   { src = gatW;  dst = wsu + GWBF_U; idx = cid - 16384; }
        else if (cid < 614400)  { src = z2nw;  dst = wsu + WZBF_U; idx = cid - 90112; }
        else return;
        float4 v = ((const float4*)src)[idx];
        us4 o; o.x = f2bf(v.x); o.y = f2bf(v.y); o.z = f2bf(v.z); o.w = f2bf(v.w);
        ((us4*)dst)[idx] = o;
    }
}

// ------------------------------------------------------------- z_to_nodes --
__global__ __launch_bounds__(256) void k_z2n(
    const float* __restrict__ bias, const float* __restrict__ lB,
    float* __restrict__ wsf)
{
    ushort* wsu = (ushort*)wsf;
    int t = threadIdx.x;
    int w = t >> 6, ln = t & 63, lo = ln & 15, hi = ln >> 4;
    int bm = blockIdx.x >> 6, bn = blockIdx.x & 63;
    int brow0 = bm * 64;
    int o0 = bn * 256 + w * 64;
    const ushort* wz = wsu + WZBF_U;
    const ushort* zb = wsu + ZBF_U;
    float4v acc[4][4];
    #pragma unroll
    for (int m = 0; m < 4; ++m)
        #pragma unroll
        for (int n = 0; n < 4; ++n) acc[m][n] = (float4v)(0.f);
    #pragma unroll
    for (int kk = 0; kk < 4; ++kk) {
        short8v a[4], bq[4];
        #pragma unroll
        for (int m = 0; m < 4; ++m)
            a[m] = *(const short8v*)(wz + (size_t)(o0 + m*16 + lo)*128 + kk*32 + hi*8);
        #pragma unroll
        for (int n = 0; n < 4; ++n)
            bq[n] = *(const short8v*)(zb + (size_t)(brow0 + n*16 + lo)*128 + kk*32 + hi*8);
        #pragma unroll
        for (int m = 0; m < 4; ++m)
            #pragma unroll
            for (int n = 0; n < 4; ++n)
                acc[m][n] = __builtin_amdgcn_mfma_f32_16x16x32_bf16(a[m], bq[n], acc[m][n], 0, 0, 0);
    }
    const float* zA = wsf + ZA_OFF;
    float4 za0[4], za1[4];
    #pragma unroll
    for (int n = 0; n < 4; ++n) {
        int brow = brow0 + n*16 + lo;
        za0[n] = *(const float4*)&zA[brow*8];
        za1[n] = *(const float4*)&zA[brow*8 + 4];
    }
    #pragma unroll
    for (int m = 0; m < 4; ++m) {
        float lor[4][4]; float bs[4];
        #pragma unroll
        for (int q = 0; q < 4; ++q) {
            int o = o0 + m*16 + hi*4 + q;
            float4 b20 = *(const float4*)&lB[(size_t)o*8];
            float4 b21 = *(const float4*)&lB[(size_t)o*8 + 4];
            bs[q] = bias[o];
            #pragma unroll
            for (int n = 0; n < 4; ++n)
                lor[n][q] = za0[n].x*b20.x + za0[n].y*b20.y + za0[n].z*b20.z + za0[n].w*b20.w
                          + za1[n].x*b21.x + za1[n].y*b21.y + za1[n].z*b21.z + za1[n].w*b21.w;
        }
        #pragma unroll
        for (int n = 0; n < 4; ++n) {
            int brow = brow0 + n*16 + lo;
            float v0 = acc[m][n][0] + 2.f*lor[n][0] + bs[0]; v0 = v0 > 0.f ? v0 : 0.f;
            float v1 = acc[m][n][1] + 2.f*lor[n][1] + bs[1]; v1 = v1 > 0.f ? v1 : 0.f;
            float v2 = acc[m][n][2] + 2.f*lor[n][2] + bs[2]; v2 = v2 > 0.f ? v2 : 0.f;
            float v3 = acc[m][n][3] + 2.f*lor[n][3] + bs[3]; v3 = v3 > 0.f ? v3 : 0.f;
            us4 pk; pk.x = f2bf(v0); pk.y = f2bf(v1); pk.z = f2bf(v2); pk.w = f2bf(v3);
            *(us4*)(wsu + XBF_U + (size_t)brow*16384 + o0 + m*16 + hi*4) = pk;
        }
    }
}

// -------------------------------------- fused: 3 GAT layers + predictors ---
// one block per graph, 8 waves = (head, node-half). R region alternates
// x-mode (swizzled) <-> hT-mode per layer; 4 barriers/layer.
__global__ __launch_bounds__(512, 4) void k_fused(
    const float* __restrict__ asrc_all, const float* __restrict__ adst_all,
    const float* __restrict__ gbias,
    const float* __restrict__ nodeb, const float* __restrict__ adjb,
    const float* __restrict__ bondb,
    float* __restrict__ wsf, float* __restrict__ out)
{
    __shared__ ushort Rr[18432];   // 36 KB: x-mode (16384 used) / hT-mode [4][64][72]
    __shared__ float scr[768];     // layers: es[0..255], ed[256..511]; pred: aux
    ushort* wsu = (ushort*)wsf;
    int t = threadIdx.x;
    int w = t >> 6, ln = t & 63, lo = ln & 15, hi = ln >> 4;
    int head = w & 3, m0 = (w >> 2) * 32;
    int b = blockIdx.x;
    const ushort* xb  = wsu + XBF_U + (size_t)b * 16384;
    const ushort* zbp = wsu + ZBF_U + (size_t)b * 128;

    // ---- stage x[b] -> R (x-mode, swizzled)
    #pragma unroll
    for (int i = 0; i < 4; ++i) {
        int flat = i*512 + t;               // 0..2047 (row, 16B-chunk)
        int r = flat >> 5, ch = flat & 31;
        short8v v = *(const short8v*)(xb + (size_t)r*256 + ch*8);
        *(short8v*)&Rr[r*256 + ((ch ^ (r & 7)) << 3)] = v;
    }
    __syncthreads();

    float* es = scr;        // [4][64]
    float* ed = scr + 256;  // [4][64]

    for (int l = 0; l < 3; ++l) {
        const ushort* wl = wsu + GWBF_U + (size_t)l*98304 + (size_t)head*24576;

        // ---- h-GEMM: rows [m0,m0+32), head's 64 channels, K=384
        float4v acc[2][4];
        #pragma unroll
        for (int m = 0; m < 2; ++m)
            #pragma unroll
            for (int n = 0; n < 4; ++n) acc[m][n] = (float4v)(0.f);
        #pragma unroll
        for (int kk = 0; kk < 12; ++kk) {
            short8v a[2], bq[4];
            if (kk < 8) {
                a[0] = *(const short8v*)&Rr[xidx(m0 + lo,      kk*32 + hi*8)];
                a[1] = *(const short8v*)&Rr[xidx(m0 + 16 + lo, kk*32 + hi*8)];
            } else {
                short8v az = *(const short8v*)(zbp + (kk-8)*32 + hi*8);
                a[0] = az; a[1] = az;
            }
            #pragma unroll
            for (int n = 0; n < 4; ++n)
                bq[n] = *(const short8v*)(wl + (size_t)(n*16 + lo)*384 + kk*32 + hi*8);
            #pragma unroll
            for (int m = 0; m < 2; ++m)
                #pragma unroll
                for (int n = 0; n < 4; ++n)
                    acc[m][n] = __builtin_amdgcn_mfma_f32_16x16x32_bf16(a[m], bq[n], acc[m][n], 0, 0, 0);
        }

        // ---- e-dots for my 32 rows
        float asv[4], adv[4];
        #pragma unroll
        for (int n = 0; n < 4; ++n) {
            asv[n] = asrc_all[l*256 + head*64 + n*16 + lo];
            adv[n] = adst_all[l*256 + head*64 + n*16 + lo];
        }
        #pragma unroll
        for (int m = 0; m < 2; ++m) {
            float ps0=0,ps1=0,ps2=0,ps3=0, pd0=0,pd1=0,pd2=0,pd3=0;
            #pragma unroll
            for (int n = 0; n < 4; ++n) {
                ps0 += acc[m][n][0]*asv[n]; pd0 += acc[m][n][0]*adv[n];
                ps1 += acc[m][n][1]*asv[n]; pd1 += acc[m][n][1]*adv[n];
                ps2 += acc[m][n][2]*asv[n]; pd2 += acc[m][n][2]*adv[n];
                ps3 += acc[m][n][3]*asv[n]; pd3 += acc[m][n][3]*adv[n];
            }
            #pragma unroll
            for (int mask = 1; mask < 16; mask <<= 1) {
                ps0 += __shfl_xor(ps0, mask); pd0 += __shfl_xor(pd0, mask);
                ps1 += __shfl_xor(ps1, mask); pd1 += __shfl_xor(pd1, mask);
                ps2 += __shfl_xor(ps2, mask); pd2 += __shfl_xor(pd2, mask);
                ps3 += __shfl_xor(ps3, mask); pd3 += __shfl_xor(pd3, mask);
            }
            if (lo == 0) {
                *(float4*)&es[head*64 + m0 + m*16 + hi*4] = make_float4(ps0, ps1, ps2, ps3);
                *(float4*)&ed[head*64 + m0 + m*16 + hi*4] = make_float4(pd0, pd1, pd2, pd3);
            }
        }

        __syncthreads();    // sync_a: all x-mode reads done

        // ---- hT write (R -> hT-mode): hT[head][c][j]
        #pragma unroll
        for (int m = 0; m < 2; ++m)
            #pragma unroll
            for (int n = 0; n < 4; ++n) {
                us4 pk;
                pk.x = f2bf(acc[m][n][0]); pk.y = f2bf(acc[m][n][1]);
                pk.z = f2bf(acc[m][n][2]); pk.w = f2bf(acc[m][n][3]);
                *(us4*)&Rr[head*4608 + (n*16 + lo)*72 + (m0 + m*16 + hi*4)] = pk;
            }

        __syncthreads();    // sync_b: hT + es/ed visible

        // ---- PV (swapped): out^T[c][r] = sum_j h[j][c] * p[r][j], p=exp(leaky(e))
        float4v acc2[4][2];
        #pragma unroll
        for (int m = 0; m < 4; ++m)
            #pragma unroll
            for (int n = 0; n < 2; ++n) acc2[m][n] = (float4v)(0.f);
        float psum[2] = {0.f, 0.f};
        #pragma unroll
        for (int kk = 0; kk < 2; ++kk) {
            short8v hb[4];
            #pragma unroll
            for (int m = 0; m < 4; ++m)
                hb[m] = *(const short8v*)&Rr[head*4608 + (m*16 + lo)*72 + kk*32 + hi*8];
            float4 e0 = *(const float4*)&es[head*64 + kk*32 + hi*8];
            float4 e1 = *(const float4*)&es[head*64 + kk*32 + hi*8 + 4];
            float ej[8] = {e0.x, e0.y, e0.z, e0.w, e1.x, e1.y, e1.z, e1.w};
            #pragma unroll
            for (int n = 0; n < 2; ++n) {
                float edr = ed[head*64 + m0 + n*16 + lo];
                short8v af; float pp = 0.f;
                #pragma unroll
                for (int jj = 0; jj < 8; ++jj) {
                    float e = edr + ej[jj];
                    e = fmaxf(e, 0.2f * e);
                    float p = __expf(e);
                    pp += p;
                    af[jj] = (short)f2bf(p);
                }
                psum[n] += pp;
                #pragma unroll
                for (int m = 0; m < 4; ++m)
                    acc2[m][n] = __builtin_amdgcn_mfma_f32_16x16x32_bf16(hb[m], af, acc2[m][n], 0, 0, 0);
            }
        }
        float rs[2];
        #pragma unroll
        for (int n = 0; n < 2; ++n) {
            psum[n] += __shfl_xor(psum[n], 16);
            psum[n] += __shfl_xor(psum[n], 32);
            rs[n] = 1.0f / psum[n];
        }

        __syncthreads();    // sync_c: all hT reads done

        // ---- new-x write to R (x-mode)
        #pragma unroll
        for (int m = 0; m < 4; ++m) {
            int c0 = head*64 + m*16 + hi*4;
            float b0 = gbias[l*256 + c0 + 0];
            float b1 = gbias[l*256 + c0 + 1];
            float b2 = gbias[l*256 + c0 + 2];
            float b3 = gbias[l*256 + c0 + 3];
            #pragma unroll
            for (int n = 0; n < 2; ++n) {
                int r = m0 + n*16 + lo;
                float v0 = acc2[m][n][0]*rs[n] + b0; v0 = v0 > 0.f ? v0 : 0.f;
                float v1 = acc2[m][n][1]*rs[n] + b1; v1 = v1 > 0.f ? v1 : 0.f;
                float v2 = acc2[m][n][2]*rs[n] + b2; v2 = v2 > 0.f ? v2 : 0.f;
                float v3 = acc2[m][n][3]*rs[n] + b3; v3 = v3 > 0.f ? v3 : 0.f;
                us4 pk; pk.x = f2bf(v0); pk.y = f2bf(v1); pk.z = f2bf(v2); pk.w = f2bf(v3);
                *(us4*)&Rr[xidx(r, c0)] = pk;
            }
        }

        __syncthreads();    // sync_d: new x ready
    }

    // --------------------------------------------------------- predictors --
    const ushort* pw = wsu + PW_U;
    int g = w & 3;
    if (w < 4) {
        float4v p0 = (float4v)(0.f), p1 = (float4v)(0.f), p2 = (float4v)(0.f);
        #pragma unroll
        for (int kk = 0; kk < 8; ++kk) {
            short8v a  = *(const short8v*)&Rr[xidx(g*16 + lo, kk*32 + hi*8)];
            short8v b0 = *(const short8v*)(pw + (size_t)(lo)*256      + kk*32 + hi*8);
            short8v b1 = *(const short8v*)(pw + (size_t)(16 + lo)*256 + kk*32 + hi*8);
            short8v b2 = *(const short8v*)(pw + (size_t)(32 + lo)*256 + kk*32 + hi*8);
            p0 = __builtin_amdgcn_mfma_f32_16x16x32_bf16(a, b0, p0, 0, 0, 0);
            p1 = __builtin_amdgcn_mfma_f32_16x16x32_bf16(a, b1, p1, 0, 0, 0);
            p2 = __builtin_amdgcn_mfma_f32_16x16x32_bf16(a, b2, p2, 0, 0, 0);
        }
        float bs0 = nodeb[lo], bs1 = nodeb[16 + lo], bs2 = nodeb[32 + lo];
        #pragma unroll
        for (int q = 0; q < 4; ++q) {
            int nd = g*16 + hi*4 + q;
            out[(size_t)b*4096 + (size_t)nd*64 + lo]      = p0[q] + bs0;
            out[(size_t)b*4096 + (size_t)nd*64 + 16 + lo] = p1[q] + bs1;
            out[(size_t)b*4096 + (size_t)nd*64 + 32 + lo] = p2[q] + bs2;
        }
    } else {
        float4v p3 = (float4v)(0.f), p4 = (float4v)(0.f);
        #pragma unroll
        for (int kk = 0; kk < 8; ++kk) {
            short8v a  = *(const short8v*)&Rr[xidx(g*16 + lo, kk*32 + hi*8)];
            short8v b3 = *(const short8v*)(pw + (size_t)(48 + lo)*256 + kk*32 + hi*8);
            short8v b4 = *(const short8v*)(pw + (size_t)(64 + lo)*256 + kk*32 + hi*8);
            p3 = __builtin_amdgcn_mfma_f32_16x16x32_bf16(a, b3, p3, 0, 0, 0);
            p4 = __builtin_amdgcn_mfma_f32_16x16x32_bf16(a, b4, p4, 0, 0, 0);
        }
        float bs3 = nodeb[48 + lo];
        #pragma unroll
        for (int q = 0; q < 4; ++q) {
            int nd = g*16 + hi*4 + q;
            out[(size_t)b*4096 + (size_t)nd*64 + 48 + lo] = p3[q] + bs3;
            float v = p4[q];
            if (lo == 0)      scr[nd] = v;                       // s1
            else if (lo == 1) scr[64 + nd] = v;                  // s2
            else if (lo < 6)  scr[128 + nd*5 + (lo-2)] = v;      // t1[nd][0..3]
            else if (lo < 10) scr[448 + nd*5 + (lo-6)] = v;      // t2[nd][0..3]
        }
    }
    __syncthreads();

    // adj logits: contiguous float4 sweep over 512 threads
    float ab = adjb[0];
    #pragma unroll
    for (int it = 0; it < 2; ++it) {
        int flat = (it*512 + t) * 4;
        int i = flat >> 6, j0 = flat & 63;
        float4 v; float* vp = (float*)&v;
        #pragma unroll
        for (int uu = 0; uu < 4; ++uu) {
            int j = j0 + uu;
            float val;
            if (i == j)      val = 0.f;
            else if (i < j)  val = scr[i] + scr[64 + j] + ab;
            else             val = scr[j] + scr[64 + i] + ab;
            vp[uu] = val;
        }
        *(float4*)&out[2097152UL + (size_t)b*4096 + flat] = v;
    }

    // bond logits: contiguous float4 sweep
    float4 bb = *(const float4*)bondb;
    #pragma unroll
    for (int it = 0; it < 8; ++it) {
        int fl4 = it*512 + t;
        int i = fl4 >> 6, j = fl4 & 63;
        float4 v;
        if (i == j) { v.x = v.y = v.z = v.w = 0.f; }
        else {
            int a2 = i < j ? i : j, c2 = i < j ? j : i;
            v.x = scr[128 + a2*5 + 0] + scr[448 + c2*5 + 0] + bb.x;
            v.y = scr[128 + a2*5 + 1] + scr[448 + c2*5 + 1] + bb.y;
            v.z = scr[128 + a2*5 + 2] + scr[448 + c2*5 + 2] + bb.z;
            v.w = scr[128 + a2*5 + 3] + scr[448 + c2*5 + 3] + bb.w;
        }
        *(float4*)&out[4194304UL + (size_t)b*16384 + (size_t)fl4*4] = v;
    }
}

// ------------------------------------------------------------------ host ---
extern "C" void kernel_launch(void* const* d_in, const int* in_sizes, int n_in,
                              void* d_out, int out_size, void* d_ws, size_t ws_size,
                              hipStream_t stream)
{
    const float* z     = (const float*)d_in[0];
    const float* z2nw  = (const float*)d_in[1];
    const float* z2nb  = (const float*)d_in[2];
    const float* z2nA  = (const float*)d_in[3];
    const float* z2nB  = (const float*)d_in[4];
    const float* gatW  = (const float*)d_in[5];
    const float* asrc  = (const float*)d_in[6];
    const float* adst  = (const float*)d_in[7];
    const float* gbias = (const float*)d_in[8];
    const float* nodew = (const float*)d_in[9];
    const float* nodeb = (const float*)d_in[10];
    const float* nodeA = (const float*)d_in[11];
    const float* nodeB = (const float*)d_in[12];
    const float* adjw  = (const float*)d_in[13];
    const float* adjb  = (const float*)d_in[14];
    const float* adjA  = (const float*)d_in[15];
    const float* adjB  = (const float*)d_in[16];
    const float* bondw = (const float*)d_in[17];
    const float* bondb = (const float*)d_in[18];
    const float* bondA = (const float*)d_in[19];
    const float* bondB = (const float*)d_in[20];
    float* ws  = (float*)d_ws;
    float* out = (float*)d_out;

    k_setup<<<2496, 256, 0, stream>>>(z, z2nA, nodew, nodeA, nodeB,
                                      adjw, adjA, adjB, bondw, bondA, bondB,
                                      gatW, z2nw, ws);
    k_z2n<<<512, 256, 0, stream>>>(z2nb, z2nB, ws);
    k_fused<<<512, 512, 0, stream>>>(asrc, adst, gbias, nodeb, adjb, bondb, ws, out);
}